// Round 7
// baseline (320.102 us; speedup 1.0000x reference)
//
#include <hip/hip_runtime.h>
#include <math.h>

// B=32, OBS=768, D=512, V=64
// Outputs (f32): h[32*512] | pred[32*768] | graph[64*64] | reasoning[32*512]
// 3 kernels: front (enc1,Ea,Eb,gia) -> mega (per-b: z,gi,GRU,pred,r1,Cc,rs2) -> score.
// NOTE (round 5): persistent kernel + agent-scope grid barriers = ~145us/barrier
// on gfx950 (L2 wb/inv per block + same-line spin contention). Do not retry.
// NOTE (round 6): each dispatch boundary ~4.5us; mid-chain stage kernels were
// ~18us each (latency-bound) -> fused into per-b megakernel (all row-wise in b).

#if __has_builtin(__builtin_amdgcn_exp2f)
#define EXP2F __builtin_amdgcn_exp2f
#else
#define EXP2F exp2f
#endif

typedef float f32x2 __attribute__((ext_vector_type(2)));

__device__ __forceinline__ float gelu_exact(float x) {
    return 0.5f * x * (1.f + erff(x * 0.70710678118654752f));
}
__device__ __forceinline__ float sigmoid_fast(float v) {
    return __builtin_amdgcn_rcpf(1.f + EXP2F(-1.442695041f * v));
}
__device__ __forceinline__ float tanh_fast(float v) {
    return fmaf(-2.f, __builtin_amdgcn_rcpf(1.f + EXP2F(2.885390082f * v)), 1.f);
}

// ---------------- front: wave-tile GEMM (unchanged from round 6) ----------------
template<int NF4, int ACT>
__device__ __forceinline__ void wgemm(int wid,
        const float* __restrict__ A, int lda,
        const float* __restrict__ W, int ldw,
        const float* __restrict__ bias,
        float* __restrict__ out, int ldo,
        int oblocks) {
    int lane = threadIdx.x & 63;
    int oblock = wid % oblocks;
    int bgroup = wid / oblocks;
    int o0 = oblock * 8, b0 = bgroup * 8;

    float4 w[8][NF4];
#pragma unroll
    for (int r = 0; r < 8; ++r) {
        const float4* wr = reinterpret_cast<const float4*>(W + (o0 + r) * ldw);
#pragma unroll
        for (int c = 0; c < NF4; ++c) w[r][c] = wr[c * 64 + lane];
    }
#pragma unroll 2
    for (int bi = 0; bi < 8; ++bi) {
        const float4* ar = reinterpret_cast<const float4*>(A + (b0 + bi) * lda);
        float4 a[NF4];
#pragma unroll
        for (int c = 0; c < NF4; ++c) a[c] = ar[c * 64 + lane];
        float s[8];
#pragma unroll
        for (int r = 0; r < 8; ++r) {
            float acc = 0.f;
#pragma unroll
            for (int c = 0; c < NF4; ++c) {
                acc = fmaf(a[c].x, w[r][c].x, acc);
                acc = fmaf(a[c].y, w[r][c].y, acc);
                acc = fmaf(a[c].z, w[r][c].z, acc);
                acc = fmaf(a[c].w, w[r][c].w, acc);
            }
            s[r] = acc;
        }
#pragma unroll
        for (int m = 1; m < 64; m <<= 1) {
#pragma unroll
            for (int r = 0; r < 8; ++r) s[r] += __shfl_xor(s[r], m, 64);
        }
        if (lane == 0) {
#pragma unroll
            for (int r = 0; r < 8; ++r) {
                float v = s[r] + (bias ? bias[o0 + r] : 0.f);
                if (ACT) v = gelu_exact(v);
                out[(b0 + bi) * ldo + o0 + r] = v;
            }
        }
    }
}

// K1: enc1 (512 w) + Ea (1024) + Eb (1024) + gia = action@wih[:,512:]^T + bih (768)
__global__ void __launch_bounds__(256) front_kernel(
    const float* __restrict__ obs, const float* __restrict__ enc_w1,
    const float* __restrict__ enc_b1, float* __restrict__ h1,
    const float* __restrict__ embed, const float* __restrict__ sc_w1,
    const float* __restrict__ sc_b1, float* __restrict__ Ea, float* __restrict__ Eb,
    const float* __restrict__ action, const float* __restrict__ wih,
    const float* __restrict__ bih, float* __restrict__ gia) {
    int wid = blockIdx.x * 4 + (threadIdx.x >> 6);
    if (wid < 512) {
        wgemm<3, 1>(wid, obs, 768, enc_w1, 768, enc_b1, h1, 1024, 128);
    } else if (wid < 1536) {
        wgemm<2, 0>(wid - 512, embed, 512, sc_w1, 1536, sc_b1, Ea, 1024, 128);
    } else if (wid < 2560) {
        wgemm<2, 0>(wid - 1536, embed, 512, sc_w1 + 512, 1536, nullptr, Eb, 1024, 128);
    } else {
        wgemm<2, 0>(wid - 2560, action, 512, wih + 512, 1024, bih, gia, 1536, 192);
    }
}

// ---------------- megakernel: one block per batch row b ----------------
// 8-lane-group dot: lane = 8*grp + sub; group g owns output row (base+unit*8+g);
// sub owns k-slice f4 idx {sub + 8c}. 3-stage shuffle reduce (xor 1,2,4).
// K=512 A-row held in 16 float4 regs; W streamed from global (128B segments/row).

// dot over K=512: a[16] regs vs W row; returns per-lane partial.
__device__ __forceinline__ float dot512(const float4* __restrict__ wr, int sub,
                                        const float4 a[16]) {
    float acc = 0.f;
#pragma unroll
    for (int c = 0; c < 16; ++c) {
        float4 wv = wr[sub + 8 * c];
        acc = fmaf(a[c].x, wv.x, acc);
        acc = fmaf(a[c].y, wv.y, acc);
        acc = fmaf(a[c].z, wv.z, acc);
        acc = fmaf(a[c].w, wv.w, acc);
    }
    return acc;
}
__device__ __forceinline__ float red8(float acc) {
    acc += __shfl_xor(acc, 1, 64);
    acc += __shfl_xor(acc, 2, 64);
    acc += __shfl_xor(acc, 4, 64);
    return acc;
}

__global__ void __launch_bounds__(512) mega_kernel(
    const float* __restrict__ h1, const float* __restrict__ enc_w2,
    const float* __restrict__ enc_b2, const float* __restrict__ wih,
    const float* __restrict__ gia, const float* __restrict__ bhh,
    const float* __restrict__ action,
    const float* __restrict__ dec_w, const float* __restrict__ dec_b,
    const float* __restrict__ rs_w1, const float* __restrict__ rs_b1,
    const float* __restrict__ rs_w2, const float* __restrict__ rs_b2,
    const float* __restrict__ sc_w1,
    float* __restrict__ h_out, float* __restrict__ pred,
    float* __restrict__ reasoning, float* __restrict__ Cc) {
    __shared__ float s_h1[1024];
    __shared__ float s_z[512];
    __shared__ float s_gi[1536];
    __shared__ float s_h[512];
    __shared__ float s_ha[512];
    __shared__ float s_r1[512];

    const int b = blockIdx.x;
    const int tid = threadIdx.x;
    const int lane = tid & 63;
    const int wave = tid >> 6;      // 0..7
    const int grp = lane >> 3;      // 0..7 (output row within unit)
    const int sub = lane & 7;       // 0..7 (k-slice)

    // h1 row -> LDS (2 coalesced loads/thread)
    s_h1[tid] = h1[b * 1024 + tid];
    s_h1[tid + 512] = h1[b * 1024 + 512 + tid];
    __syncthreads();

    // ---- phase z: z[o] = h1row · enc_w2[o,:] + enc_b2[o], K=1024, 512 outputs ----
    {
        const float4* a4 = reinterpret_cast<const float4*>(s_h1);
#pragma unroll 2
        for (int u = 0; u < 8; ++u) {
            int o = wave * 64 + u * 8 + grp;
            const float4* wr = reinterpret_cast<const float4*>(enc_w2 + o * 1024);
            float acc = 0.f;
#pragma unroll
            for (int c = 0; c < 32; ++c) {
                float4 wv = wr[sub + 8 * c];
                float4 av = a4[sub + 8 * c];
                acc = fmaf(av.x, wv.x, acc);
                acc = fmaf(av.y, wv.y, acc);
                acc = fmaf(av.z, wv.z, acc);
                acc = fmaf(av.w, wv.w, acc);
            }
            acc = red8(acc);
            if (sub == 0) s_z[o] = acc + enc_b2[o];
        }
    }
    __syncthreads();

    // ---- phase gi: gi[r] = zrow · wih[r, 0:512], r in [0,1536), K=512 ----
    {
        float4 a[16];
        const float4* z4 = reinterpret_cast<const float4*>(s_z);
#pragma unroll
        for (int c = 0; c < 16; ++c) a[c] = z4[sub + 8 * c];
#pragma unroll 2
        for (int u = 0; u < 24; ++u) {
            int r = wave * 192 + u * 8 + grp;
            float acc = dot512(reinterpret_cast<const float4*>(wih + r * 1024), sub, a);
            acc = red8(acc);
            if (sub == 0) s_gi[r] = acc;
        }
    }
    __syncthreads();

    // ---- GRU elementwise (h0=0 => gh=bhh); gia already holds action-half + bih ----
    {
        int o = tid;  // 512 threads, one o each
        const float* ga = gia + b * 1536;
        float r = sigmoid_fast(s_gi[o] + ga[o] + bhh[o]);
        float u = sigmoid_fast(s_gi[512 + o] + ga[512 + o] + bhh[512 + o]);
        float n = tanh_fast(s_gi[1024 + o] + ga[1024 + o] + r * bhh[1024 + o]);
        float hv = (1.f - u) * n;
        float av = action[b * 512 + o];
        s_h[o] = hv;
        s_ha[o] = hv + av;
        h_out[b * 512 + o] = hv;
    }
    __syncthreads();

    // ---- phases pred (768, K=512 from h) & r1 (512, K=512 from h) ----
    {
        float4 a[16];
        const float4* h4 = reinterpret_cast<const float4*>(s_h);
#pragma unroll
        for (int c = 0; c < 16; ++c) a[c] = h4[sub + 8 * c];
#pragma unroll 2
        for (int u = 0; u < 12; ++u) {
            int o = wave * 96 + u * 8 + grp;
            float acc = dot512(reinterpret_cast<const float4*>(dec_w + o * 512), sub, a);
            acc = red8(acc);
            if (sub == 0) pred[b * 768 + o] = acc + dec_b[o];
        }
#pragma unroll 2
        for (int u = 0; u < 8; ++u) {
            int o = wave * 64 + u * 8 + grp;
            float acc = dot512(reinterpret_cast<const float4*>(rs_w1 + o * 512), sub, a);
            acc = red8(acc);
            if (sub == 0) s_r1[o] = gelu_exact(acc + rs_b1[o]);
        }
    }

    // ---- phase Cc: Cc[o] = ha · sc_w1[o, 1024:1536], o in [0,1024) ----
    {
        float4 a[16];
        const float4* ha4 = reinterpret_cast<const float4*>(s_ha);
#pragma unroll
        for (int c = 0; c < 16; ++c) a[c] = ha4[sub + 8 * c];
#pragma unroll 2
        for (int u = 0; u < 16; ++u) {
            int o = wave * 128 + u * 8 + grp;
            const float4* wr = reinterpret_cast<const float4*>(sc_w1 + o * 1536 + 1024);
            float acc = dot512(wr, sub, a);
            acc = red8(acc);
            if (sub == 0) Cc[b * 1024 + o] = acc;
        }
    }
    __syncthreads();  // s_r1 ready for rs2

    // ---- phase rs2: reasoning = r1 @ rs_w2^T + rs_b2, 512 outputs ----
    {
        float4 a[16];
        const float4* r4 = reinterpret_cast<const float4*>(s_r1);
#pragma unroll
        for (int c = 0; c < 16; ++c) a[c] = r4[sub + 8 * c];
#pragma unroll 2
        for (int u = 0; u < 8; ++u) {
            int o = wave * 64 + u * 8 + grp;
            float acc = dot512(reinterpret_cast<const float4*>(rs_w2 + o * 512), sub, a);
            acc = red8(acc);
            if (sub == 0) reasoning[b * 512 + o] = acc + rs_b2[o];
        }
    }
}

// ---------------- score: 2048 blocks (unchanged math from round 6) ----------------
__global__ void __launch_bounds__(256) score_kernel(
    const float* __restrict__ Ea, const float* __restrict__ Eb,
    const float* __restrict__ Cc, const float* __restrict__ w2,
    const float* __restrict__ b2, float* __restrict__ graph) {
    int blk = blockIdx.x;
    int i = blk >> 5;
    int j0 = (blk & 31) << 1;
    int lane = threadIdx.x & 63;
    int wave = threadIdx.x >> 6;
    int d0 = lane << 4;

    const float4* Ea4  = reinterpret_cast<const float4*>(Ea + i * 1024 + d0);
    const float4* Eb04 = reinterpret_cast<const float4*>(Eb + j0 * 1024 + d0);
    const float4* Eb14 = reinterpret_cast<const float4*>(Eb + (j0 + 1) * 1024 + d0);
    const float4* W4   = reinterpret_cast<const float4*>(w2 + d0);

    f32x2 basea[8], baseb[8], wv[8];
#pragma unroll
    for (int c = 0; c < 4; ++c) {
        float4 e  = Ea4[c];
        float4 f0 = Eb04[c];
        float4 f1 = Eb14[c];
        float4 w  = W4[c];
        basea[2 * c]     = f32x2{e.x + f0.x, e.y + f0.y};
        basea[2 * c + 1] = f32x2{e.z + f0.z, e.w + f0.w};
        baseb[2 * c]     = f32x2{e.x + f1.x, e.y + f1.y};
        baseb[2 * c + 1] = f32x2{e.z + f1.z, e.w + f1.w};
        wv[2 * c]        = f32x2{w.x, w.y};
        wv[2 * c + 1]    = f32x2{w.z, w.w};
    }

    const f32x2 nk2  = f32x2{-2.4554274f, -2.4554274f};  // -1.702*log2(e)
    const f32x2 one2 = f32x2{1.f, 1.f};
    float bsc = b2[0];
    float gsum0 = 0.f, gsum1 = 0.f;
    const float4* p = reinterpret_cast<const float4*>(Cc + d0 + (wave * 8) * 1024);
    float4 m0 = p[0], m1 = p[1], m2 = p[2], m3 = p[3];

    for (int r = 0; r < 8; ++r) {
        f32x2 cc[8];
        cc[0] = f32x2{m0.x, m0.y}; cc[1] = f32x2{m0.z, m0.w};
        cc[2] = f32x2{m1.x, m1.y}; cc[3] = f32x2{m1.z, m1.w};
        cc[4] = f32x2{m2.x, m2.y}; cc[5] = f32x2{m2.z, m2.w};
        cc[6] = f32x2{m3.x, m3.y}; cc[7] = f32x2{m3.z, m3.w};
        if (r < 7) {
            const float4* q = reinterpret_cast<const float4*>(Cc + (wave * 8 + r + 1) * 1024 + d0);
            m0 = q[0]; m1 = q[1]; m2 = q[2]; m3 = q[3];
        }
        float s0 = 0.f, s1 = 0.f;
#pragma unroll
        for (int e = 0; e < 8; ++e) {
            f32x2 xA = cc[e] + basea[e];
            f32x2 xB = cc[e] + baseb[e];
            f32x2 aA = xA * nk2;
            f32x2 aB = xB * nk2;
            f32x2 tA, tB;
            tA.x = EXP2F(aA.x); tA.y = EXP2F(aA.y);
            tB.x = EXP2F(aB.x); tB.y = EXP2F(aB.y);
            f32x2 dA = tA + one2;
            f32x2 dB = tB + one2;
            f32x2 pA = xA * wv[e];
            f32x2 pB = xB * wv[e];
            float numA = fmaf(pA.x, dA.y, pA.y * dA.x);
            float numB = fmaf(pB.x, dB.y, pB.y * dB.x);
            float rrA = __builtin_amdgcn_rcpf(dA.x * dA.y);
            float rrB = __builtin_amdgcn_rcpf(dB.x * dB.y);
            s0 = fmaf(numA, rrA, s0);
            s1 = fmaf(numB, rrB, s1);
        }
#pragma unroll
        for (int m = 32; m >= 1; m >>= 1) {
            s0 += __shfl_xor(s0, m, 64);
            s1 += __shfl_xor(s1, m, 64);
        }
        if (lane == 0) {
            gsum0 += sigmoid_fast(s0 + bsc);
            gsum1 += sigmoid_fast(s1 + bsc);
        }
    }

    __shared__ float red[4][2];
    if (lane == 0) { red[wave][0] = gsum0; red[wave][1] = gsum1; }
    __syncthreads();
    if (threadIdx.x == 0) {
        graph[i * 64 + j0]     = (red[0][0] + red[1][0] + red[2][0] + red[3][0]) * 0.03125f;
        graph[i * 64 + j0 + 1] = (red[0][1] + red[1][1] + red[2][1] + red[3][1]) * 0.03125f;
    }
}

extern "C" void kernel_launch(void* const* d_in, const int* in_sizes, int n_in,
                              void* d_out, int out_size, void* d_ws, size_t ws_size,
                              hipStream_t stream) {
    const float* obs     = (const float*)d_in[0];
    const float* action  = (const float*)d_in[1];
    const float* embed   = (const float*)d_in[2];
    const float* sc_w1   = (const float*)d_in[3];
    const float* sc_b1   = (const float*)d_in[4];
    const float* sc_w2   = (const float*)d_in[5];
    const float* sc_b2   = (const float*)d_in[6];
    const float* enc_w1  = (const float*)d_in[7];
    const float* enc_b1  = (const float*)d_in[8];
    const float* enc_w2  = (const float*)d_in[9];
    const float* enc_b2  = (const float*)d_in[10];
    const float* gru_wih = (const float*)d_in[11];
    const float* gru_bih = (const float*)d_in[13];
    const float* gru_bhh = (const float*)d_in[14];
    const float* dec_w   = (const float*)d_in[15];
    const float* dec_b   = (const float*)d_in[16];
    const float* rs_w1   = (const float*)d_in[17];
    const float* rs_b1   = (const float*)d_in[18];
    const float* rs_w2   = (const float*)d_in[19];
    const float* rs_b2   = (const float*)d_in[20];

    float* ws = (float*)d_ws;
    float* h1  = ws + 0;        // 32x1024
    float* gia = ws + 49152;    // 32x1536
    float* Cc  = ws + 131072;   // 32x1024
    float* Ea  = ws + 163840;   // 64x1024
    float* Eb  = ws + 229376;   // 64x1024

    float* h_out     = (float*)d_out;
    float* pred      = h_out + 16384;
    float* graph     = h_out + 40960;
    float* reasoning = h_out + 45056;

    front_kernel<<<832, 256, 0, stream>>>(obs, enc_w1, enc_b1, h1,
                                          embed, sc_w1, sc_b1, Ea, Eb,
                                          action, gru_wih, gru_bih, gia);
    mega_kernel<<<32, 512, 0, stream>>>(h1, enc_w2, enc_b2, gru_wih, gia,
                                        gru_bhh, action, dec_w, dec_b,
                                        rs_w1, rs_b1, rs_w2, rs_b2, sc_w1,
                                        h_out, pred, reasoning, Cc);
    score_kernel<<<2048, 256, 0, stream>>>(Ea, Eb, Cc, sc_w2, sc_b2, graph);
}

// Round 8
// 198.888 us; speedup vs baseline: 1.6095x; 1.6095x over previous
//
#include <hip/hip_runtime.h>
#include <math.h>

// B=32, OBS=768, D=512, V=64
// Outputs (f32): h[32*512] | pred[32*768] | graph[64*64] | reasoning[32*512]
// 5 kernels: front -> enc2 -> gigru -> mid -> score(+rs2).
// NOTE (round 5): persistent kernel + agent-scope grid barriers = ~145us/barrier
// on gfx950. Do not retry.
// NOTE (round 7): per-b megakernel (32 blocks) = 195us: 87% of CUs idle, weights
// refetched per-XCD (43MB), 230GB/s stream. Small-GEMM kernels need machine-wide
// wave coverage. Do not retry.
// Round 8: mid-chain b-tiles 8->4 (2x waves) to cover all CUs and hide load latency.

#if __has_builtin(__builtin_amdgcn_exp2f)
#define EXP2F __builtin_amdgcn_exp2f
#else
#define EXP2F exp2f
#endif

typedef float f32x2 __attribute__((ext_vector_type(2)));

__device__ __forceinline__ float gelu_exact(float x) {
    return 0.5f * x * (1.f + erff(x * 0.70710678118654752f));
}
__device__ __forceinline__ float sigmoid_fast(float v) {
    return __builtin_amdgcn_rcpf(1.f + EXP2F(-1.442695041f * v));
}
__device__ __forceinline__ float tanh_fast(float v) {
    return fmaf(-2.f, __builtin_amdgcn_rcpf(1.f + EXP2F(2.885390082f * v)), 1.f);
}

// Wave-tile GEMM: one wave -> out[b0..b0+BT-1][o0..o0+7] = act(A[b,:]·W[o,:]+bias[o]).
// K = NF4*256 floats. Lane owns float4 indices {c*64+lane}: all loads coalesced.
// bg-major unit order: same-o units are `oblocks` apart -> same XCD (L2 sharing).
template<int NF4, int ACT, int BT>
__device__ __forceinline__ void wgemm(int wid,
        const float* __restrict__ A, int lda,
        const float* __restrict__ W, int ldw,
        const float* __restrict__ bias,
        float* __restrict__ out, int ldo,
        int oblocks) {
    int lane = threadIdx.x & 63;
    int oblock = wid % oblocks;
    int bgroup = wid / oblocks;
    int o0 = oblock * 8, b0 = bgroup * BT;

    float4 w[8][NF4];
#pragma unroll
    for (int r = 0; r < 8; ++r) {
        const float4* wr = reinterpret_cast<const float4*>(W + (o0 + r) * ldw);
#pragma unroll
        for (int c = 0; c < NF4; ++c) w[r][c] = wr[c * 64 + lane];
    }
#pragma unroll 2
    for (int bi = 0; bi < BT; ++bi) {
        const float4* ar = reinterpret_cast<const float4*>(A + (b0 + bi) * lda);
        float4 a[NF4];
#pragma unroll
        for (int c = 0; c < NF4; ++c) a[c] = ar[c * 64 + lane];
        float s[8];
#pragma unroll
        for (int r = 0; r < 8; ++r) {
            float acc = 0.f;
#pragma unroll
            for (int c = 0; c < NF4; ++c) {
                acc = fmaf(a[c].x, w[r][c].x, acc);
                acc = fmaf(a[c].y, w[r][c].y, acc);
                acc = fmaf(a[c].z, w[r][c].z, acc);
                acc = fmaf(a[c].w, w[r][c].w, acc);
            }
            s[r] = acc;
        }
#pragma unroll
        for (int m = 1; m < 64; m <<= 1) {
#pragma unroll
            for (int r = 0; r < 8; ++r) s[r] += __shfl_xor(s[r], m, 64);
        }
        if (lane == 0) {
#pragma unroll
            for (int r = 0; r < 8; ++r) {
                float v = s[r] + (bias ? bias[o0 + r] : 0.f);
                if (ACT) v = gelu_exact(v);
                out[(b0 + bi) * ldo + o0 + r] = v;
            }
        }
    }
}

// K1: enc1 (512 w) + Ea (1024) + Eb (1024) + gia = action@wih[:,512:]^T + bih (768)
// = 3328 waves = 832 blocks
__global__ void __launch_bounds__(256) front_kernel(
    const float* __restrict__ obs, const float* __restrict__ enc_w1,
    const float* __restrict__ enc_b1, float* __restrict__ h1,
    const float* __restrict__ embed, const float* __restrict__ sc_w1,
    const float* __restrict__ sc_b1, float* __restrict__ Ea, float* __restrict__ Eb,
    const float* __restrict__ action, const float* __restrict__ wih,
    const float* __restrict__ bih, float* __restrict__ gia) {
    int wid = blockIdx.x * 4 + (threadIdx.x >> 6);
    if (wid < 512) {
        wgemm<3, 1, 8>(wid, obs, 768, enc_w1, 768, enc_b1, h1, 1024, 128);
    } else if (wid < 1536) {
        wgemm<2, 0, 8>(wid - 512, embed, 512, sc_w1, 1536, sc_b1, Ea, 1024, 128);
    } else if (wid < 2560) {
        wgemm<2, 0, 8>(wid - 1536, embed, 512, sc_w1 + 512, 1536, nullptr, Eb, 1024, 128);
    } else {
        wgemm<2, 0, 8>(wid - 2560, action, 512, wih + 512, 1024, bih, gia, 1536, 192);
    }
}

// K2: z = h1 @ enc_w2^T + b2. BT=4: 64 ob x 8 bg = 512 waves = 128 blocks
__global__ void __launch_bounds__(256) enc2_kernel(
    const float* __restrict__ h1, const float* __restrict__ enc_w2,
    const float* __restrict__ enc_b2, float* __restrict__ z) {
    int wid = blockIdx.x * 4 + (threadIdx.x >> 6);
    wgemm<4, 0, 4>(wid, h1, 1024, enc_w2, 1024, enc_b2, z, 512, 64);
}

// K3: z-half of gi + GRU. Wave = opair (2 o x 3 gates = 6 rows, K=512) x 4 b.
// 256 opairs x 8 bgroups = 2048 waves = 512 blocks. h0=0 => gh = bhh.
__global__ void __launch_bounds__(256) gigru_kernel(
    const float* __restrict__ z, const float* __restrict__ wih,
    const float* __restrict__ gia, const float* __restrict__ bhh,
    const float* __restrict__ action, float* __restrict__ h, float* __restrict__ ha) {
    int wid = blockIdx.x * 4 + (threadIdx.x >> 6);
    int lane = threadIdx.x & 63;
    int opair = wid & 255;
    int bg = wid >> 8;
    int o0 = opair * 2, b0 = bg * 4;

    int rows[6] = {o0, o0 + 1, 512 + o0, 513 + o0, 1024 + o0, 1025 + o0};
    float4 w[6][2];
#pragma unroll
    for (int r = 0; r < 6; ++r) {
        const float4* wr = reinterpret_cast<const float4*>(wih + rows[r] * 1024);
#pragma unroll
        for (int c = 0; c < 2; ++c) w[r][c] = wr[c * 64 + lane];
    }
    float bhr0 = bhh[o0],        bhr1 = bhh[o0 + 1];
    float bhu0 = bhh[512 + o0],  bhu1 = bhh[513 + o0];
    float bhn0 = bhh[1024 + o0], bhn1 = bhh[1025 + o0];

#pragma unroll 2
    for (int bi = 0; bi < 4; ++bi) {
        int b = b0 + bi;
        const float4* ar = reinterpret_cast<const float4*>(z + b * 512);
        float4 a[2] = {ar[lane], ar[64 + lane]};
        float s[6];
#pragma unroll
        for (int r = 0; r < 6; ++r) {
            float acc = 0.f;
#pragma unroll
            for (int c = 0; c < 2; ++c) {
                acc = fmaf(a[c].x, w[r][c].x, acc);
                acc = fmaf(a[c].y, w[r][c].y, acc);
                acc = fmaf(a[c].z, w[r][c].z, acc);
                acc = fmaf(a[c].w, w[r][c].w, acc);
            }
            s[r] = acc;
        }
#pragma unroll
        for (int m = 1; m < 64; m <<= 1) {
#pragma unroll
            for (int r = 0; r < 6; ++r) s[r] += __shfl_xor(s[r], m, 64);
        }
        if (lane == 0) {
            const float* gb = gia + b * 1536;
            float r0 = sigmoid_fast(s[0] + gb[o0]        + bhr0);
            float r1 = sigmoid_fast(s[1] + gb[o0 + 1]    + bhr1);
            float u0 = sigmoid_fast(s[2] + gb[512 + o0]  + bhu0);
            float u1 = sigmoid_fast(s[3] + gb[513 + o0]  + bhu1);
            float n0 = tanh_fast(s[4] + gb[1024 + o0] + r0 * bhn0);
            float n1 = tanh_fast(s[5] + gb[1025 + o0] + r1 * bhn1);
            float hv0 = (1.f - u0) * n0;
            float hv1 = (1.f - u1) * n1;
            h[b * 512 + o0]      = hv0;
            h[b * 512 + o0 + 1]  = hv1;
            ha[b * 512 + o0]     = hv0 + action[b * 512 + o0];
            ha[b * 512 + o0 + 1] = hv1 + action[b * 512 + o0 + 1];
        }
    }
}

// K4: BT=4: dec (96 ob) + rs1 (64) + Cc (128), x8 bg = 2304 waves = 576 blocks
__global__ void __launch_bounds__(256) mid_kernel(
    const float* __restrict__ h, const float* __restrict__ ha,
    const float* __restrict__ dec_w, const float* __restrict__ dec_b, float* __restrict__ pred,
    const float* __restrict__ rs_w1, const float* __restrict__ rs_b1, float* __restrict__ r1,
    const float* __restrict__ sc_w1, float* __restrict__ Cc) {
    int wid = blockIdx.x * 4 + (threadIdx.x >> 6);
    if (wid < 768) {
        wgemm<2, 0, 4>(wid, h, 512, dec_w, 512, dec_b, pred, 768, 96);
    } else if (wid < 1280) {
        wgemm<2, 1, 4>(wid - 768, h, 512, rs_w1, 512, rs_b1, r1, 512, 64);
    } else {
        wgemm<2, 0, 4>(wid - 1280, ha, 512, sc_w1 + 1024, 1536, nullptr, Cc, 1024, 128);
    }
}

// K5: 2048 blocks. Blocks 0..63 also run rs2 first (256 units, BT=8).
// Score: block=(i, j0..j0+1); wave w -> b in [8w,8w+8); lane -> d [16*lane,+16).
__global__ void __launch_bounds__(256) score_rs2_kernel(
    const float* __restrict__ Ea, const float* __restrict__ Eb,
    const float* __restrict__ Cc, const float* __restrict__ w2,
    const float* __restrict__ b2, float* __restrict__ graph,
    const float* __restrict__ r1, const float* __restrict__ rs_w2,
    const float* __restrict__ rs_b2, float* __restrict__ reasoning) {
    int blk = blockIdx.x;
    if (blk < 64) {
        int wid = blk * 4 + (threadIdx.x >> 6);
        wgemm<2, 0, 8>(wid, r1, 512, rs_w2, 512, rs_b2, reasoning, 512, 64);
    }
    int i = blk >> 5;
    int j0 = (blk & 31) << 1;
    int lane = threadIdx.x & 63;
    int wave = threadIdx.x >> 6;
    int d0 = lane << 4;

    const float4* Ea4  = reinterpret_cast<const float4*>(Ea + i * 1024 + d0);
    const float4* Eb04 = reinterpret_cast<const float4*>(Eb + j0 * 1024 + d0);
    const float4* Eb14 = reinterpret_cast<const float4*>(Eb + (j0 + 1) * 1024 + d0);
    const float4* W4   = reinterpret_cast<const float4*>(w2 + d0);

    f32x2 basea[8], baseb[8], wv[8];
#pragma unroll
    for (int c = 0; c < 4; ++c) {
        float4 e  = Ea4[c];
        float4 f0 = Eb04[c];
        float4 f1 = Eb14[c];
        float4 w  = W4[c];
        basea[2 * c]     = f32x2{e.x + f0.x, e.y + f0.y};
        basea[2 * c + 1] = f32x2{e.z + f0.z, e.w + f0.w};
        baseb[2 * c]     = f32x2{e.x + f1.x, e.y + f1.y};
        baseb[2 * c + 1] = f32x2{e.z + f1.z, e.w + f1.w};
        wv[2 * c]        = f32x2{w.x, w.y};
        wv[2 * c + 1]    = f32x2{w.z, w.w};
    }

    const f32x2 nk2  = f32x2{-2.4554274f, -2.4554274f};  // -1.702*log2(e)
    const f32x2 one2 = f32x2{1.f, 1.f};
    float bsc = b2[0];
    float gsum0 = 0.f, gsum1 = 0.f;
    const float4* p = reinterpret_cast<const float4*>(Cc + d0 + (wave * 8) * 1024);
    float4 m0 = p[0], m1 = p[1], m2 = p[2], m3 = p[3];

    for (int r = 0; r < 8; ++r) {
        f32x2 cc[8];
        cc[0] = f32x2{m0.x, m0.y}; cc[1] = f32x2{m0.z, m0.w};
        cc[2] = f32x2{m1.x, m1.y}; cc[3] = f32x2{m1.z, m1.w};
        cc[4] = f32x2{m2.x, m2.y}; cc[5] = f32x2{m2.z, m2.w};
        cc[6] = f32x2{m3.x, m3.y}; cc[7] = f32x2{m3.z, m3.w};
        if (r < 7) {
            const float4* q = reinterpret_cast<const float4*>(Cc + (wave * 8 + r + 1) * 1024 + d0);
            m0 = q[0]; m1 = q[1]; m2 = q[2]; m3 = q[3];
        }
        float s0 = 0.f, s1 = 0.f;
#pragma unroll
        for (int e = 0; e < 8; ++e) {
            f32x2 xA = cc[e] + basea[e];
            f32x2 xB = cc[e] + baseb[e];
            f32x2 aA = xA * nk2;
            f32x2 aB = xB * nk2;
            f32x2 tA, tB;
            tA.x = EXP2F(aA.x); tA.y = EXP2F(aA.y);
            tB.x = EXP2F(aB.x); tB.y = EXP2F(aB.y);
            f32x2 dA = tA + one2;
            f32x2 dB = tB + one2;
            f32x2 pA = xA * wv[e];
            f32x2 pB = xB * wv[e];
            float numA = fmaf(pA.x, dA.y, pA.y * dA.x);
            float numB = fmaf(pB.x, dB.y, pB.y * dB.x);
            float rrA = __builtin_amdgcn_rcpf(dA.x * dA.y);
            float rrB = __builtin_amdgcn_rcpf(dB.x * dB.y);
            s0 = fmaf(numA, rrA, s0);
            s1 = fmaf(numB, rrB, s1);
        }
#pragma unroll
        for (int m = 32; m >= 1; m >>= 1) {
            s0 += __shfl_xor(s0, m, 64);
            s1 += __shfl_xor(s1, m, 64);
        }
        if (lane == 0) {
            gsum0 += sigmoid_fast(s0 + bsc);
            gsum1 += sigmoid_fast(s1 + bsc);
        }
    }

    __shared__ float red[4][2];
    if (lane == 0) { red[wave][0] = gsum0; red[wave][1] = gsum1; }
    __syncthreads();
    if (threadIdx.x == 0) {
        graph[i * 64 + j0]     = (red[0][0] + red[1][0] + red[2][0] + red[3][0]) * 0.03125f;
        graph[i * 64 + j0 + 1] = (red[0][1] + red[1][1] + red[2][1] + red[3][1]) * 0.03125f;
    }
}

extern "C" void kernel_launch(void* const* d_in, const int* in_sizes, int n_in,
                              void* d_out, int out_size, void* d_ws, size_t ws_size,
                              hipStream_t stream) {
    const float* obs     = (const float*)d_in[0];
    const float* action  = (const float*)d_in[1];
    const float* embed   = (const float*)d_in[2];
    const float* sc_w1   = (const float*)d_in[3];
    const float* sc_b1   = (const float*)d_in[4];
    const float* sc_w2   = (const float*)d_in[5];
    const float* sc_b2   = (const float*)d_in[6];
    const float* enc_w1  = (const float*)d_in[7];
    const float* enc_b1  = (const float*)d_in[8];
    const float* enc_w2  = (const float*)d_in[9];
    const float* enc_b2  = (const float*)d_in[10];
    const float* gru_wih = (const float*)d_in[11];
    const float* gru_bih = (const float*)d_in[13];
    const float* gru_bhh = (const float*)d_in[14];
    const float* dec_w   = (const float*)d_in[15];
    const float* dec_b   = (const float*)d_in[16];
    const float* rs_w1   = (const float*)d_in[17];
    const float* rs_b1   = (const float*)d_in[18];
    const float* rs_w2   = (const float*)d_in[19];
    const float* rs_b2   = (const float*)d_in[20];

    float* ws = (float*)d_ws;
    float* h1  = ws + 0;        // 32x1024
    float* z   = ws + 32768;    // 32x512
    float* gia = ws + 49152;    // 32x1536
    float* ha  = ws + 98304;    // 32x512
    float* r1  = ws + 114688;   // 32x512
    float* Cc  = ws + 131072;   // 32x1024
    float* Ea  = ws + 163840;   // 64x1024
    float* Eb  = ws + 229376;   // 64x1024

    float* h_out     = (float*)d_out;
    float* pred      = h_out + 16384;
    float* graph     = h_out + 40960;
    float* reasoning = h_out + 45056;

    front_kernel<<<832, 256, 0, stream>>>(obs, enc_w1, enc_b1, h1,
                                          embed, sc_w1, sc_b1, Ea, Eb,
                                          action, gru_wih, gru_bih, gia);
    enc2_kernel<<<128, 256, 0, stream>>>(h1, enc_w2, enc_b2, z);
    gigru_kernel<<<512, 256, 0, stream>>>(z, gru_wih, gia, gru_bhh, action, h_out, ha);
    mid_kernel<<<576, 256, 0, stream>>>(h_out, ha, dec_w, dec_b, pred,
                                        rs_w1, rs_b1, r1, sc_w1, Cc);
    score_rs2_kernel<<<2048, 256, 0, stream>>>(Ea, Eb, Cc, sc_w2, sc_b2, graph,
                                               r1, rs_w2, rs_b2, reasoning);
}

// Round 9
// 172.756 us; speedup vs baseline: 1.8529x; 1.1513x over previous
//
#include <hip/hip_runtime.h>
#include <math.h>

// B=32, OBS=768, D=512, V=64
// Outputs (f32): h[32*512] | pred[32*768] | graph[64*64] | reasoning[32*512]
// 5 kernels: front -> enc2 -> gigru -> mid -> score(+rs2).
// NOTE (round 5): persistent kernel + agent-scope grid barriers = ~145us/barrier. No.
// NOTE (round 7): per-b megakernel (32 blocks) starves 87% of CUs. No.
// Round 9: fully-unrolled score loop, persistent accumulators + single multi-value
// merge reduction (17 DS vs 96); wgemm merge reduction (10 DS vs 48); BT 4->2.

#if __has_builtin(__builtin_amdgcn_exp2f)
#define EXP2F __builtin_amdgcn_exp2f
#else
#define EXP2F exp2f
#endif

__device__ __forceinline__ float gelu_exact(float x) {
    return 0.5f * x * (1.f + erff(x * 0.70710678118654752f));
}
__device__ __forceinline__ float sigmoid_fast(float v) {
    return __builtin_amdgcn_rcpf(1.f + EXP2F(-1.442695041f * v));
}
__device__ __forceinline__ float tanh_fast(float v) {
    return fmaf(-2.f, __builtin_amdgcn_rcpf(1.f + EXP2F(2.885390082f * v)), 1.f);
}

// Wave-tile GEMM: one wave -> out[b0..b0+BT-1][o0..o0+7].
// Merge-based reduction: 10 DS ops total; lanes 0..7 hold the 8 outputs.
template<int NF4, int ACT, int BT>
__device__ __forceinline__ void wgemm(int wid,
        const float* __restrict__ A, int lda,
        const float* __restrict__ W, int ldw,
        const float* __restrict__ bias,
        float* __restrict__ out, int ldo,
        int oblocks) {
    int lane = threadIdx.x & 63;
    int oblock = wid % oblocks;
    int bgroup = wid / oblocks;
    int o0 = oblock * 8, b0 = bgroup * BT;

    float4 w[8][NF4];
#pragma unroll
    for (int r = 0; r < 8; ++r) {
        const float4* wr = reinterpret_cast<const float4*>(W + (o0 + r) * ldw);
#pragma unroll
        for (int c = 0; c < NF4; ++c) w[r][c] = wr[c * 64 + lane];
    }
    float bv = bias ? bias[o0 + (lane & 7)] : 0.f;
    bool p0 = lane & 1, p1 = lane & 2, p2 = lane & 4;

#pragma unroll
    for (int bi = 0; bi < BT; ++bi) {
        const float4* ar = reinterpret_cast<const float4*>(A + (b0 + bi) * lda);
        float4 a[NF4];
#pragma unroll
        for (int c = 0; c < NF4; ++c) a[c] = ar[c * 64 + lane];
        float s[8];
#pragma unroll
        for (int r = 0; r < 8; ++r) {
            float acc = 0.f;
#pragma unroll
            for (int c = 0; c < NF4; ++c) {
                acc = fmaf(a[c].x, w[r][c].x, acc);
                acc = fmaf(a[c].y, w[r][c].y, acc);
                acc = fmaf(a[c].z, w[r][c].z, acc);
                acc = fmaf(a[c].w, w[r][c].w, acc);
            }
            s[r] = acc;
        }
        // merge reduction: value index = lane&7, then butterfly to full sum
        float m[4];
#pragma unroll
        for (int k = 0; k < 4; ++k) {
            float keep = p0 ? s[2 * k + 1] : s[2 * k];
            float send = p0 ? s[2 * k] : s[2 * k + 1];
            m[k] = keep + __shfl_xor(send, 1, 64);
        }
        float n[2];
#pragma unroll
        for (int k = 0; k < 2; ++k) {
            float keep = p1 ? m[2 * k + 1] : m[2 * k];
            float send = p1 ? m[2 * k] : m[2 * k + 1];
            n[k] = keep + __shfl_xor(send, 2, 64);
        }
        float F;
        {
            float keep = p2 ? n[1] : n[0];
            float send = p2 ? n[0] : n[1];
            F = keep + __shfl_xor(send, 4, 64);
        }
        F += __shfl_xor(F, 8, 64);
        F += __shfl_xor(F, 16, 64);
        F += __shfl_xor(F, 32, 64);
        float v = F + bv;
        if (ACT) v = gelu_exact(v);
        if (lane < 8) out[(b0 + bi) * ldo + o0 + lane] = v;
    }
}

// K1: enc1 (512 w) + Ea (1024) + Eb (1024) + gia (768) = 3328 waves = 832 blocks
__global__ void __launch_bounds__(256) front_kernel(
    const float* __restrict__ obs, const float* __restrict__ enc_w1,
    const float* __restrict__ enc_b1, float* __restrict__ h1,
    const float* __restrict__ embed, const float* __restrict__ sc_w1,
    const float* __restrict__ sc_b1, float* __restrict__ Ea, float* __restrict__ Eb,
    const float* __restrict__ action, const float* __restrict__ wih,
    const float* __restrict__ bih, float* __restrict__ gia) {
    int wid = blockIdx.x * 4 + (threadIdx.x >> 6);
    if (wid < 512) {
        wgemm<3, 1, 8>(wid, obs, 768, enc_w1, 768, enc_b1, h1, 1024, 128);
    } else if (wid < 1536) {
        wgemm<2, 0, 8>(wid - 512, embed, 512, sc_w1, 1536, sc_b1, Ea, 1024, 128);
    } else if (wid < 2560) {
        wgemm<2, 0, 8>(wid - 1536, embed, 512, sc_w1 + 512, 1536, nullptr, Eb, 1024, 128);
    } else {
        wgemm<2, 0, 8>(wid - 2560, action, 512, wih + 512, 1024, bih, gia, 1536, 192);
    }
}

// K2: z = h1 @ enc_w2^T + b2. BT=2: 64 ob x 16 bg = 1024 waves = 256 blocks
__global__ void __launch_bounds__(256) enc2_kernel(
    const float* __restrict__ h1, const float* __restrict__ enc_w2,
    const float* __restrict__ enc_b2, float* __restrict__ z) {
    int wid = blockIdx.x * 4 + (threadIdx.x >> 6);
    wgemm<4, 0, 2>(wid, h1, 1024, enc_w2, 1024, enc_b2, z, 512, 64);
}

// K3: z-half of gi + GRU. Wave = opair (6 rows, K=512) x 2 b.
// 256 opairs x 16 bgroups = 4096 waves = 1024 blocks. h0=0 => gh = bhh.
__global__ void __launch_bounds__(256) gigru_kernel(
    const float* __restrict__ z, const float* __restrict__ wih,
    const float* __restrict__ gia, const float* __restrict__ bhh,
    const float* __restrict__ action, float* __restrict__ h, float* __restrict__ ha) {
    int wid = blockIdx.x * 4 + (threadIdx.x >> 6);
    int lane = threadIdx.x & 63;
    int opair = wid & 255;
    int bg = wid >> 8;
    int o0 = opair * 2, b0 = bg * 2;

    int rows[6] = {o0, o0 + 1, 512 + o0, 513 + o0, 1024 + o0, 1025 + o0};
    float4 w[6][2];
#pragma unroll
    for (int r = 0; r < 6; ++r) {
        const float4* wr = reinterpret_cast<const float4*>(wih + rows[r] * 1024);
#pragma unroll
        for (int c = 0; c < 2; ++c) w[r][c] = wr[c * 64 + lane];
    }
    float bhr0 = bhh[o0],        bhr1 = bhh[o0 + 1];
    float bhu0 = bhh[512 + o0],  bhu1 = bhh[513 + o0];
    float bhn0 = bhh[1024 + o0], bhn1 = bhh[1025 + o0];

#pragma unroll
    for (int bi = 0; bi < 2; ++bi) {
        int b = b0 + bi;
        const float4* ar = reinterpret_cast<const float4*>(z + b * 512);
        float4 a[2] = {ar[lane], ar[64 + lane]};
        float s[6];
#pragma unroll
        for (int r = 0; r < 6; ++r) {
            float acc = 0.f;
#pragma unroll
            for (int c = 0; c < 2; ++c) {
                acc = fmaf(a[c].x, w[r][c].x, acc);
                acc = fmaf(a[c].y, w[r][c].y, acc);
                acc = fmaf(a[c].z, w[r][c].z, acc);
                acc = fmaf(a[c].w, w[r][c].w, acc);
            }
            s[r] = acc;
        }
#pragma unroll
        for (int m = 1; m < 64; m <<= 1) {
#pragma unroll
            for (int r = 0; r < 6; ++r) s[r] += __shfl_xor(s[r], m, 64);
        }
        if (lane == 0) {
            const float* gb = gia + b * 1536;
            float r0 = sigmoid_fast(s[0] + gb[o0]        + bhr0);
            float r1 = sigmoid_fast(s[1] + gb[o0 + 1]    + bhr1);
            float u0 = sigmoid_fast(s[2] + gb[512 + o0]  + bhu0);
            float u1 = sigmoid_fast(s[3] + gb[513 + o0]  + bhu1);
            float n0 = tanh_fast(s[4] + gb[1024 + o0] + r0 * bhn0);
            float n1 = tanh_fast(s[5] + gb[1025 + o0] + r1 * bhn1);
            float hv0 = (1.f - u0) * n0;
            float hv1 = (1.f - u1) * n1;
            h[b * 512 + o0]      = hv0;
            h[b * 512 + o0 + 1]  = hv1;
            ha[b * 512 + o0]     = hv0 + action[b * 512 + o0];
            ha[b * 512 + o0 + 1] = hv1 + action[b * 512 + o0 + 1];
        }
    }
}

// K4: BT=2: dec (96 ob) + rs1 (64) + Cc (128), x16 bg = 4608 waves = 1152 blocks
__global__ void __launch_bounds__(256) mid_kernel(
    const float* __restrict__ h, const float* __restrict__ ha,
    const float* __restrict__ dec_w, const float* __restrict__ dec_b, float* __restrict__ pred,
    const float* __restrict__ rs_w1, const float* __restrict__ rs_b1, float* __restrict__ r1,
    const float* __restrict__ sc_w1, float* __restrict__ Cc) {
    int wid = blockIdx.x * 4 + (threadIdx.x >> 6);
    if (wid < 1536) {
        wgemm<2, 0, 2>(wid, h, 512, dec_w, 512, dec_b, pred, 768, 96);
    } else if (wid < 2560) {
        wgemm<2, 1, 2>(wid - 1536, h, 512, rs_w1, 512, rs_b1, r1, 512, 64);
    } else {
        wgemm<2, 0, 2>(wid - 2560, ha, 512, sc_w1 + 1024, 1536, nullptr, Cc, 1024, 128);
    }
}

// K5: 2048 blocks. Blocks 0..63 also run rs2 first (256 waves, BT=8).
// Score: block=(i, j0..j0+1); wave w -> b in [8w,8w+8); lane -> d [16*lane,+16).
// Persistent accumulators sA/sB[8]; single 16-way merge reduction at the end.
__global__ void __launch_bounds__(256) score_rs2_kernel(
    const float* __restrict__ Ea, const float* __restrict__ Eb,
    const float* __restrict__ Cc, const float* __restrict__ w2,
    const float* __restrict__ b2, float* __restrict__ graph,
    const float* __restrict__ r1, const float* __restrict__ rs_w2,
    const float* __restrict__ rs_b2, float* __restrict__ reasoning) {
    int blk = blockIdx.x;
    if (blk < 64) {
        int wid = blk * 4 + (threadIdx.x >> 6);
        wgemm<2, 0, 8>(wid, r1, 512, rs_w2, 512, rs_b2, reasoning, 512, 64);
    }
    int i = blk >> 5;
    int j0 = (blk & 31) << 1;
    int lane = threadIdx.x & 63;
    int wave = threadIdx.x >> 6;
    int d0 = lane << 4;

    const float4* Ea4  = reinterpret_cast<const float4*>(Ea + i * 1024 + d0);
    const float4* Eb04 = reinterpret_cast<const float4*>(Eb + j0 * 1024 + d0);
    const float4* Eb14 = reinterpret_cast<const float4*>(Eb + (j0 + 1) * 1024 + d0);
    const float4* W4   = reinterpret_cast<const float4*>(w2 + d0);

    float basea[16], baseb[16], wv[16];
#pragma unroll
    for (int c = 0; c < 4; ++c) {
        float4 e  = Ea4[c];
        float4 f0 = Eb04[c];
        float4 f1 = Eb14[c];
        float4 w  = W4[c];
        basea[4 * c + 0] = e.x + f0.x; basea[4 * c + 1] = e.y + f0.y;
        basea[4 * c + 2] = e.z + f0.z; basea[4 * c + 3] = e.w + f0.w;
        baseb[4 * c + 0] = e.x + f1.x; baseb[4 * c + 1] = e.y + f1.y;
        baseb[4 * c + 2] = e.z + f1.z; baseb[4 * c + 3] = e.w + f1.w;
        wv[4 * c + 0] = w.x; wv[4 * c + 1] = w.y;
        wv[4 * c + 2] = w.z; wv[4 * c + 3] = w.w;
    }

    const float NK = -2.4554274f;  // -1.702 * log2(e)
    float sA[8], sB[8];
#pragma unroll
    for (int b = 0; b < 8; ++b) { sA[b] = 0.f; sB[b] = 0.f; }

    const float* ccbase = Cc + (wave * 8) * 1024 + d0;
#pragma unroll
    for (int b = 0; b < 8; ++b) {
        const float4* q = reinterpret_cast<const float4*>(ccbase + b * 1024);
        float4 c0 = q[0], c1 = q[1], c2 = q[2], c3 = q[3];
        float cc[16] = {c0.x, c0.y, c0.z, c0.w, c1.x, c1.y, c1.z, c1.w,
                        c2.x, c2.y, c2.z, c2.w, c3.x, c3.y, c3.z, c3.w};
#pragma unroll
        for (int e = 0; e < 16; e += 2) {
            float xa0 = cc[e] + basea[e];
            float xa1 = cc[e + 1] + basea[e + 1];
            float ta0 = EXP2F(xa0 * NK);
            float ta1 = EXP2F(xa1 * NK);
            float da0 = 1.f + ta0, da1 = 1.f + ta1;
            float numa = fmaf(xa0 * wv[e], da1, (xa1 * wv[e + 1]) * da0);
            sA[b] = fmaf(numa, __builtin_amdgcn_rcpf(da0 * da1), sA[b]);

            float xb0 = cc[e] + baseb[e];
            float xb1 = cc[e + 1] + baseb[e + 1];
            float tb0 = EXP2F(xb0 * NK);
            float tb1 = EXP2F(xb1 * NK);
            float db0 = 1.f + tb0, db1 = 1.f + tb1;
            float numb = fmaf(xb0 * wv[e], db1, (xb1 * wv[e + 1]) * db0);
            sB[b] = fmaf(numb, __builtin_amdgcn_rcpf(db0 * db1), sB[b]);
        }
    }

    // 16-way merge reduction: final value index = (j = lane&1, b = (lane>>1)&7)
    bool p0 = lane & 1, p1 = lane & 2, p2 = lane & 4, p3 = lane & 8;
    float m[8];
#pragma unroll
    for (int k = 0; k < 8; ++k) {
        float keep = p0 ? sB[k] : sA[k];
        float send = p0 ? sA[k] : sB[k];
        m[k] = keep + __shfl_xor(send, 1, 64);
    }
    float n[4];
#pragma unroll
    for (int k = 0; k < 4; ++k) {
        float keep = p1 ? m[2 * k + 1] : m[2 * k];
        float send = p1 ? m[2 * k] : m[2 * k + 1];
        n[k] = keep + __shfl_xor(send, 2, 64);
    }
    float o2[2];
#pragma unroll
    for (int k = 0; k < 2; ++k) {
        float keep = p2 ? n[2 * k + 1] : n[2 * k];
        float send = p2 ? n[2 * k] : n[2 * k + 1];
        o2[k] = keep + __shfl_xor(send, 4, 64);
    }
    float F;
    {
        float keep = p3 ? o2[1] : o2[0];
        float send = p3 ? o2[0] : o2[1];
        F = keep + __shfl_xor(send, 8, 64);
    }
    F += __shfl_xor(F, 16, 64);
    F += __shfl_xor(F, 32, 64);

    // sigmoid wave-wide, then sum over b (lane bits 1..3)
    float sig = sigmoid_fast(F + b2[0]);
    sig += __shfl_xor(sig, 2, 64);
    sig += __shfl_xor(sig, 4, 64);
    sig += __shfl_xor(sig, 8, 64);

    __shared__ float red[4][2];
    if (lane < 2) red[wave][lane] = sig;
    __syncthreads();
    if (threadIdx.x < 2) {
        graph[i * 64 + j0 + threadIdx.x] =
            (red[0][threadIdx.x] + red[1][threadIdx.x] +
             red[2][threadIdx.x] + red[3][threadIdx.x]) * 0.03125f;
    }
}

extern "C" void kernel_launch(void* const* d_in, const int* in_sizes, int n_in,
                              void* d_out, int out_size, void* d_ws, size_t ws_size,
                              hipStream_t stream) {
    const float* obs     = (const float*)d_in[0];
    const float* action  = (const float*)d_in[1];
    const float* embed   = (const float*)d_in[2];
    const float* sc_w1   = (const float*)d_in[3];
    const float* sc_b1   = (const float*)d_in[4];
    const float* sc_w2   = (const float*)d_in[5];
    const float* sc_b2   = (const float*)d_in[6];
    const float* enc_w1  = (const float*)d_in[7];
    const float* enc_b1  = (const float*)d_in[8];
    const float* enc_w2  = (const float*)d_in[9];
    const float* enc_b2  = (const float*)d_in[10];
    const float* gru_wih = (const float*)d_in[11];
    const float* gru_bih = (const float*)d_in[13];
    const float* gru_bhh = (const float*)d_in[14];
    const float* dec_w   = (const float*)d_in[15];
    const float* dec_b   = (const float*)d_in[16];
    const float* rs_w1   = (const float*)d_in[17];
    const float* rs_b1   = (const float*)d_in[18];
    const float* rs_w2   = (const float*)d_in[19];
    const float* rs_b2   = (const float*)d_in[20];

    float* ws = (float*)d_ws;
    float* h1  = ws + 0;        // 32x1024
    float* z   = ws + 32768;    // 32x512
    float* gia = ws + 49152;    // 32x1536
    float* ha  = ws + 98304;    // 32x512
    float* r1  = ws + 114688;   // 32x512
    float* Cc  = ws + 131072;   // 32x1024
    float* Ea  = ws + 163840;   // 64x1024
    float* Eb  = ws + 229376;   // 64x1024

    float* h_out     = (float*)d_out;
    float* pred      = h_out + 16384;
    float* graph     = h_out + 40960;
    float* reasoning = h_out + 45056;

    front_kernel<<<832, 256, 0, stream>>>(obs, enc_w1, enc_b1, h1,
                                          embed, sc_w1, sc_b1, Ea, Eb,
                                          action, gru_wih, gru_bih, gia);
    enc2_kernel<<<256, 256, 0, stream>>>(h1, enc_w2, enc_b2, z);
    gigru_kernel<<<1024, 256, 0, stream>>>(z, gru_wih, gia, gru_bhh, action, h_out, ha);
    mid_kernel<<<1152, 256, 0, stream>>>(h_out, ha, dec_w, dec_b, pred,
                                         rs_w1, rs_b1, r1, sc_w1, Cc);
    score_rs2_kernel<<<2048, 256, 0, stream>>>(Ea, Eb, Cc, sc_w2, sc_b2, graph,
                                               r1, rs_w2, rs_b2, reasoning);
}